// Round 13
// baseline (52.125 us; speedup 1.0000x reference)
//
#include <hip/hip_runtime.h>
#include <hip/hip_bf16.h>
#include <math.h>

#define NSENT 256
#define SLEN  512
#define VROWS 50000
#define EDIM  300
#define NROW  12
#define NSTEP 10              // ceil(300/32) K-steps of 16x16x32 MFMA
#define NTILE 3125            // 16-row tiles; 3125*16 = 50000 exact
#define CNT_OFF (8u << 20)    // barrier counter at +8MB in d_ws

typedef __attribute__((ext_vector_type(8))) short bf16x8;
typedef __attribute__((ext_vector_type(4))) float f32x4;

static __device__ __forceinline__ short f2bf(float f) {
    __hip_bfloat16 h = __float2bfloat16(f);   // RNE
    short s;
    __builtin_memcpy(&s, &h, sizeof(s));
    return s;
}

// ---------------------------------------------------------------------------
// Fused kernel, attempt 3. 256 blocks x 512 thr, launch_bounds(512,2):
// cap 256 VGPR (rounds 7/10 collapsed to 64 under (...,4) caps of 128).
// 1 block/CU -> all 256 blocks co-resident -> spin barrier deadlock-free.
// Phase A: wave gw does tile gw (and tile gw+2048 if < 3125) - exact cover.
//   Round-8 half-batched body (40 VGPR staging peak). B-frags in LDS.
// Barrier: counter zeroed per call by 4B hipMemsetAsync.
// Phase B: 512-thr finish (round-1 structure, exact); sent/biases prefetched
//   before the barrier so their loads drain during the spin.
// ---------------------------------------------------------------------------
__global__ __launch_bounds__(512, 2)
void textcnn_fused(const int*   __restrict__ sent,
                   const float* __restrict__ emb,
                   const float* __restrict__ k3, const float* __restrict__ b3,
                   const float* __restrict__ k4, const float* __restrict__ b4,
                   const float* __restrict__ k5, const float* __restrict__ b5,
                   const float* __restrict__ fcw, const float* __restrict__ fcb,
                   float* __restrict__ out,
                   float* __restrict__ s,
                   unsigned int* __restrict__ cnt)
{
    __shared__ bf16x8 bfrag_lds[NSTEP * 64];   // 10.25 KB
    __shared__ float  s_lds[NROW * SLEN];      // 24 KB
    __shared__ float  red[8][3];

    const int tid  = threadIdx.x;
    const int lane = tid & 63;
    const int wave = tid >> 6;      // 0..7
    const int rc   = lane & 15;     // A-row-in-tile / D-col (conv row)
    const int kg   = lane >> 4;     // k-group 0..3

    const int gw = blockIdx.x * 8 + wave;      // 0..2047

    // ---- tile 0 (gw < 2048 <= always active): issue half-0 loads FIRST ----
    const int vb0 = gw * 16;
    const float* arow0 = emb + (size_t)(vb0 + rc) * EDIM;
    float4 a0[5], a1[5];
    #pragma unroll
    for (int i = 0; i < 5; ++i) {
        const int k0 = i * 32 + kg * 8;        // <= 152: always in-bounds
        a0[i] = *reinterpret_cast<const float4*>(arow0 + k0);
        a1[i] = *reinterpret_cast<const float4*>(arow0 + k0 + 4);
    }

    // ---- B-frag build overlaps the half-0 load drain ----------------------
    for (int e = tid; e < NSTEP * 64; e += 512) {
        const int st  = e >> 6;
        const int le  = e & 63;
        const int rce = le & 15;
        const int kge = le >> 4;
        const float* krow = nullptr;
        if      (rce < 3)  krow = k3 + rce * EDIM;
        else if (rce < 7)  krow = k4 + (rce - 3) * EDIM;
        else if (rce < 12) krow = k5 + (rce - 7) * EDIM;
        const int k0 = st * 32 + kge * 8;
        float4 b0 = make_float4(0.f,0.f,0.f,0.f);
        float4 b1 = make_float4(0.f,0.f,0.f,0.f);
        if (krow) {
            if (k0 + 4 <= EDIM) b0 = *reinterpret_cast<const float4*>(krow + k0);
            if (k0 + 8 <= EDIM) b1 = *reinterpret_cast<const float4*>(krow + k0 + 4);
        }
        bf16x8 f;
        f[0]=f2bf(b0.x); f[1]=f2bf(b0.y); f[2]=f2bf(b0.z); f[3]=f2bf(b0.w);
        f[4]=f2bf(b1.x); f[5]=f2bf(b1.y); f[6]=f2bf(b1.z); f[7]=f2bf(b1.w);
        bfrag_lds[e] = f;
    }
    __syncthreads();

    // ---- tile 0: half-1 loads, then 10 MFMAs ------------------------------
    {
        float4 c0[5], c1[5];
        #pragma unroll
        for (int i = 0; i < 5; ++i) {
            const int k0 = (5 + i) * 32 + kg * 8;
            c0[i] = (k0 + 4 <= EDIM)
                  ? *reinterpret_cast<const float4*>(arow0 + k0)
                  : make_float4(0.f,0.f,0.f,0.f);
            c1[i] = (k0 + 8 <= EDIM)
                  ? *reinterpret_cast<const float4*>(arow0 + k0 + 4)
                  : make_float4(0.f,0.f,0.f,0.f);
        }
        f32x4 acc = {0.f, 0.f, 0.f, 0.f};
        #pragma unroll
        for (int i = 0; i < 5; ++i) {
            const bf16x8 bf = bfrag_lds[i * 64 + lane];
            bf16x8 af;
            af[0]=f2bf(a0[i].x); af[1]=f2bf(a0[i].y);
            af[2]=f2bf(a0[i].z); af[3]=f2bf(a0[i].w);
            af[4]=f2bf(a1[i].x); af[5]=f2bf(a1[i].y);
            af[6]=f2bf(a1[i].z); af[7]=f2bf(a1[i].w);
            acc = __builtin_amdgcn_mfma_f32_16x16x32_bf16(af, bf, acc, 0,0,0);
        }
        #pragma unroll
        for (int i = 0; i < 5; ++i) {
            const bf16x8 bf = bfrag_lds[(5 + i) * 64 + lane];
            bf16x8 af;
            af[0]=f2bf(c0[i].x); af[1]=f2bf(c0[i].y);
            af[2]=f2bf(c0[i].z); af[3]=f2bf(c0[i].w);
            af[4]=f2bf(c1[i].x); af[5]=f2bf(c1[i].y);
            af[6]=f2bf(c1[i].z); af[7]=f2bf(c1[i].w);
            acc = __builtin_amdgcn_mfma_f32_16x16x32_bf16(af, bf, acc, 0,0,0);
        }
        if (rc < NROW) {
            #pragma unroll
            for (int j = 0; j < 4; ++j)
                s[(size_t)(vb0 + kg * 4 + j) * NROW + rc] = acc[j];
        }
    }

    // ---- tile 1 (waves gw < 1077): tiles 2048..3124 -----------------------
    if (gw + 2048 < NTILE) {
        const int vb1 = (gw + 2048) * 16;
        const float* arow1 = emb + (size_t)(vb1 + rc) * EDIM;
        float4 d0[5], d1[5];
        #pragma unroll
        for (int i = 0; i < 5; ++i) {
            const int k0 = i * 32 + kg * 8;
            d0[i] = *reinterpret_cast<const float4*>(arow1 + k0);
            d1[i] = *reinterpret_cast<const float4*>(arow1 + k0 + 4);
        }
        float4 e0[5], e1[5];
        #pragma unroll
        for (int i = 0; i < 5; ++i) {
            const int k0 = (5 + i) * 32 + kg * 8;
            e0[i] = (k0 + 4 <= EDIM)
                  ? *reinterpret_cast<const float4*>(arow1 + k0)
                  : make_float4(0.f,0.f,0.f,0.f);
            e1[i] = (k0 + 8 <= EDIM)
                  ? *reinterpret_cast<const float4*>(arow1 + k0 + 4)
                  : make_float4(0.f,0.f,0.f,0.f);
        }
        f32x4 acc = {0.f, 0.f, 0.f, 0.f};
        #pragma unroll
        for (int i = 0; i < 5; ++i) {
            const bf16x8 bf = bfrag_lds[i * 64 + lane];
            bf16x8 af;
            af[0]=f2bf(d0[i].x); af[1]=f2bf(d0[i].y);
            af[2]=f2bf(d0[i].z); af[3]=f2bf(d0[i].w);
            af[4]=f2bf(d1[i].x); af[5]=f2bf(d1[i].y);
            af[6]=f2bf(d1[i].z); af[7]=f2bf(d1[i].w);
            acc = __builtin_amdgcn_mfma_f32_16x16x32_bf16(af, bf, acc, 0,0,0);
        }
        #pragma unroll
        for (int i = 0; i < 5; ++i) {
            const bf16x8 bf = bfrag_lds[(5 + i) * 64 + lane];
            bf16x8 af;
            af[0]=f2bf(e0[i].x); af[1]=f2bf(e0[i].y);
            af[2]=f2bf(e0[i].z); af[3]=f2bf(e0[i].w);
            af[4]=f2bf(e1[i].x); af[5]=f2bf(e1[i].y);
            af[6]=f2bf(e1[i].z); af[7]=f2bf(e1[i].w);
            acc = __builtin_amdgcn_mfma_f32_16x16x32_bf16(af, bf, acc, 0,0,0);
        }
        if (rc < NROW) {
            #pragma unroll
            for (int j = 0; j < 4; ++j)
                s[(size_t)(vb1 + kg * 4 + j) * NROW + rc] = acc[j];
        }
    }

    // ---- prefetch phase-B inputs (drain during the barrier spin) ----------
    const int b    = blockIdx.x;
    const int t    = tid;
    const int widx = sent[b * SLEN + t];
    const float bb3 = b3[0], bb4 = b4[0], bb5 = b5[0];

    // ================= device barrier (release/acquire) ====================
    __syncthreads();
    if (tid == 0) {
        __hip_atomic_fetch_add(cnt, 1u, __ATOMIC_RELEASE,
                               __HIP_MEMORY_SCOPE_AGENT);
        while (__hip_atomic_load(cnt, __ATOMIC_ACQUIRE,
                                 __HIP_MEMORY_SCOPE_AGENT) < (unsigned)NSENT)
            __builtin_amdgcn_s_sleep(2);
    }
    __syncthreads();

    // ================= Phase B: finish sentence b ==========================
    {
        const float4* sv = reinterpret_cast<const float4*>(s + (size_t)widx * NROW);
        const float4 sa = sv[0], sb = sv[1], sc = sv[2];
        s_lds[ 0*SLEN + t] = sa.x;  s_lds[ 1*SLEN + t] = sa.y;
        s_lds[ 2*SLEN + t] = sa.z;  s_lds[ 3*SLEN + t] = sa.w;
        s_lds[ 4*SLEN + t] = sb.x;  s_lds[ 5*SLEN + t] = sb.y;
        s_lds[ 6*SLEN + t] = sb.z;  s_lds[ 7*SLEN + t] = sb.w;
        s_lds[ 8*SLEN + t] = sc.x;  s_lds[ 9*SLEN + t] = sc.y;
        s_lds[10*SLEN + t] = sc.z;  s_lds[11*SLEN + t] = sc.w;
        __syncthreads();

        float m3 = -1e30f, m4 = -1e30f, m5 = -1e30f;
        if (t < SLEN - 2)
            m3 = tanhf(s_lds[0*SLEN + t] + s_lds[1*SLEN + t+1] +
                       s_lds[2*SLEN + t+2] + bb3);
        if (t < SLEN - 3)
            m4 = tanhf(s_lds[3*SLEN + t] + s_lds[4*SLEN + t+1] +
                       s_lds[5*SLEN + t+2] + s_lds[6*SLEN + t+3] + bb4);
        if (t < SLEN - 4)
            m5 = tanhf(s_lds[7*SLEN + t] + s_lds[8*SLEN + t+1] +
                       s_lds[9*SLEN + t+2] + s_lds[10*SLEN + t+3] +
                       s_lds[11*SLEN + t+4] + bb5);

        #pragma unroll
        for (int off = 32; off; off >>= 1) {
            m3 = fmaxf(m3, __shfl_xor(m3, off));
            m4 = fmaxf(m4, __shfl_xor(m4, off));
            m5 = fmaxf(m5, __shfl_xor(m5, off));
        }
        if (lane == 0) { red[wave][0]=m3; red[wave][1]=m4; red[wave][2]=m5; }
        __syncthreads();

        if (tid == 0) {
            float f3 = red[0][0], f4 = red[0][1], f5 = red[0][2];
            #pragma unroll
            for (int w = 1; w < 8; ++w) {
                f3 = fmaxf(f3, red[w][0]);
                f4 = fmaxf(f4, red[w][1]);
                f5 = fmaxf(f5, red[w][2]);
            }
            float lg[10];
            float mx = -1e30f;
            #pragma unroll
            for (int c = 0; c < 10; ++c) {
                lg[c] = fcb[c] + f3 * fcw[c*3+0] + f4 * fcw[c*3+1]
                               + f5 * fcw[c*3+2];
                mx = fmaxf(mx, lg[c]);
            }
            float ssum = 0.f;
            #pragma unroll
            for (int c = 0; c < 10; ++c) ssum += expf(lg[c] - mx);
            const float lse = logf(ssum);
            #pragma unroll
            for (int c = 0; c < 10; ++c) out[b * 10 + c] = lg[c] - mx - lse;
        }
    }
}

extern "C" void kernel_launch(void* const* d_in, const int* in_sizes, int n_in,
                              void* d_out, int out_size, void* d_ws, size_t ws_size,
                              hipStream_t stream) {
    const int*   sent = (const int*)  d_in[0];
    const float* emb  = (const float*)d_in[1];
    const float* k3   = (const float*)d_in[2];
    const float* b3   = (const float*)d_in[3];
    const float* k4   = (const float*)d_in[4];
    const float* b4   = (const float*)d_in[5];
    const float* k5   = (const float*)d_in[6];
    const float* b5   = (const float*)d_in[7];
    const float* fcw  = (const float*)d_in[8];
    const float* fcb  = (const float*)d_in[9];
    float* out = (float*)d_out;
    float* s   = (float*)d_ws;                                   // 2.4 MB
    unsigned int* cnt = (unsigned int*)((char*)d_ws + CNT_OFF);  // barrier ctr

    hipMemsetAsync(cnt, 0, 4, stream);    // stateless per-call barrier reset
    textcnn_fused<<<NSENT, 512, 0, stream>>>(sent, emb, k3, b3, k4, b4,
                                             k5, b5, fcw, fcb, out, s, cnt);
}

// Round 14
// 23.905 us; speedup vs baseline: 2.1805x; 2.1805x over previous
//
#include <hip/hip_runtime.h>
#include <hip/hip_bf16.h>
#include <math.h>

#define NSENT 256
#define SLEN  512
#define VROWS 50000
#define EDIM  300
#define NROW  12
#define SSTR  16          // score-row stride (floats): 64B -> 1 cache line/row
#define NSTEP 10          // ceil(300/32) K-steps of 16x16x32 MFMA

typedef __attribute__((ext_vector_type(8))) short bf16x8;
typedef __attribute__((ext_vector_type(4))) float f32x4;

static __device__ __forceinline__ short f2bf(float f) {
    __hip_bfloat16 h = __float2bfloat16(f);   // RNE
    short s;
    __builtin_memcpy(&s, &h, sizeof(s));
    return s;
}

// ---------------------------------------------------------------------------
// Kernel A (round-8 body, proven 24.6us total): vocab scores via bf16 MFMA.
// Only change: score rows stored at stride 16 floats (64B) so kernel B's
// gathers are single-cache-line.
// ---------------------------------------------------------------------------
__global__ __launch_bounds__(256, 4)
void vocab_scores_mfma(const float* __restrict__ emb,
                       const float* __restrict__ k3,
                       const float* __restrict__ k4,
                       const float* __restrict__ k5,
                       float* __restrict__ s)
{
    __shared__ bf16x8 bfrag_lds[NSTEP * 64];   // 10 KB

    const int tid  = threadIdx.x;
    const int lane = tid & 63;
    const int wave = tid >> 6;      // 0..3
    const int rc   = lane & 15;     // A-row-in-tile / D-col (conv row)
    const int kg   = lane >> 4;     // k-group 0..3

    // ---- build B fragments cooperatively (weights ~14KB, L1/L2-hot) ------
    for (int e = tid; e < NSTEP * 64; e += 256) {
        const int st  = e >> 6;
        const int le  = e & 63;
        const int rce = le & 15;
        const int kge = le >> 4;
        const float* krow = nullptr;
        if      (rce < 3)  krow = k3 + rce * EDIM;
        else if (rce < 7)  krow = k4 + (rce - 3) * EDIM;
        else if (rce < 12) krow = k5 + (rce - 7) * EDIM;
        const int k0 = st * 32 + kge * 8;
        float4 b0 = make_float4(0.f,0.f,0.f,0.f);
        float4 b1 = make_float4(0.f,0.f,0.f,0.f);
        if (krow) {
            if (k0 + 4 <= EDIM) b0 = *reinterpret_cast<const float4*>(krow + k0);
            if (k0 + 8 <= EDIM) b1 = *reinterpret_cast<const float4*>(krow + k0 + 4);
        }
        bf16x8 f;
        f[0]=f2bf(b0.x); f[1]=f2bf(b0.y); f[2]=f2bf(b0.z); f[3]=f2bf(b0.w);
        f[4]=f2bf(b1.x); f[5]=f2bf(b1.y); f[6]=f2bf(b1.z); f[7]=f2bf(b1.w);
        bfrag_lds[e] = f;
    }
    __syncthreads();

    const int vbase = blockIdx.x * 64 + wave * 16;
    const int vrow  = min(vbase + rc, VROWS - 1);    // clamp tail; stores guarded
    const float* arow = emb + (size_t)vrow * EDIM;

    f32x4 acc = {0.f, 0.f, 0.f, 0.f};

    #pragma unroll
    for (int half = 0; half < 2; ++half) {
        // batch 5 K-steps of A loads (10 float4 = 40 VGPR live)
        float4 a0[5], a1[5];
        #pragma unroll
        for (int i = 0; i < 5; ++i) {
            const int k0 = (half * 5 + i) * 32 + kg * 8;
            a0[i] = (k0 + 4 <= EDIM)
                  ? *reinterpret_cast<const float4*>(arow + k0)
                  : make_float4(0.f,0.f,0.f,0.f);
            a1[i] = (k0 + 8 <= EDIM)
                  ? *reinterpret_cast<const float4*>(arow + k0 + 4)
                  : make_float4(0.f,0.f,0.f,0.f);
        }
        #pragma unroll
        for (int i = 0; i < 5; ++i) {
            const int st = half * 5 + i;
            const bf16x8 bf = bfrag_lds[st * 64 + lane];   // ds_read_b128
            bf16x8 af;
            af[0]=f2bf(a0[i].x); af[1]=f2bf(a0[i].y);
            af[2]=f2bf(a0[i].z); af[3]=f2bf(a0[i].w);
            af[4]=f2bf(a1[i].x); af[5]=f2bf(a1[i].y);
            af[6]=f2bf(a1[i].z); af[7]=f2bf(a1[i].w);
            acc = __builtin_amdgcn_mfma_f32_16x16x32_bf16(af, bf, acc, 0, 0, 0);
        }
    }

    // store D: 4 vocab rows per lane-group, stride-16 rows
    if (rc < NROW) {
        #pragma unroll
        for (int j = 0; j < 4; ++j) {
            const int v = vbase + kg * 4 + j;
            if (v < VROWS) s[(size_t)v * SSTR + rc] = acc[j];
        }
    }
}

// ---------------------------------------------------------------------------
// Kernel B: 512 thr / sentence, 1 token/thread. sent load -> 3 independent
// float4 gathers (same 64B-aligned row = 1 line) -> LDS planes -> windows +
// tanh + max + fc + log_softmax.
// ---------------------------------------------------------------------------
__global__ __launch_bounds__(512, 1)
void textcnn_finish(const int*   __restrict__ sent,
                    const float* __restrict__ s,
                    const float* __restrict__ b3,
                    const float* __restrict__ b4,
                    const float* __restrict__ b5,
                    const float* __restrict__ fcw,
                    const float* __restrict__ fcb,
                    float* __restrict__ out)
{
    __shared__ float s_lds[NROW * SLEN];
    __shared__ float red[8][3];

    const int b = blockIdx.x;
    const int t = threadIdx.x;

    // issue the dependent chain as early as possible
    const int widx = sent[b * SLEN + t];
    const float4* row = reinterpret_cast<const float4*>(s + (size_t)widx * SSTR);
    const float4 sa = row[0];
    const float4 sb = row[1];
    const float4 sc = row[2];

    const float bb3 = b3[0], bb4 = b4[0], bb5 = b5[0];   // scalar loads

    s_lds[ 0*SLEN + t] = sa.x;  s_lds[ 1*SLEN + t] = sa.y;
    s_lds[ 2*SLEN + t] = sa.z;  s_lds[ 3*SLEN + t] = sa.w;
    s_lds[ 4*SLEN + t] = sb.x;  s_lds[ 5*SLEN + t] = sb.y;
    s_lds[ 6*SLEN + t] = sb.z;  s_lds[ 7*SLEN + t] = sb.w;
    s_lds[ 8*SLEN + t] = sc.x;  s_lds[ 9*SLEN + t] = sc.y;
    s_lds[10*SLEN + t] = sc.z;  s_lds[11*SLEN + t] = sc.w;
    __syncthreads();

    float m3 = -1e30f, m4 = -1e30f, m5 = -1e30f;
    if (t < SLEN - 2)
        m3 = tanhf(s_lds[0*SLEN + t] + s_lds[1*SLEN + t+1] +
                   s_lds[2*SLEN + t+2] + bb3);
    if (t < SLEN - 3)
        m4 = tanhf(s_lds[3*SLEN + t] + s_lds[4*SLEN + t+1] +
                   s_lds[5*SLEN + t+2] + s_lds[6*SLEN + t+3] + bb4);
    if (t < SLEN - 4)
        m5 = tanhf(s_lds[7*SLEN + t] + s_lds[8*SLEN + t+1] +
                   s_lds[9*SLEN + t+2] + s_lds[10*SLEN + t+3] +
                   s_lds[11*SLEN + t+4] + bb5);

    #pragma unroll
    for (int off = 32; off; off >>= 1) {
        m3 = fmaxf(m3, __shfl_xor(m3, off));
        m4 = fmaxf(m4, __shfl_xor(m4, off));
        m5 = fmaxf(m5, __shfl_xor(m5, off));
    }
    if ((t & 63) == 0) {
        const int w = t >> 6;
        red[w][0] = m3; red[w][1] = m4; red[w][2] = m5;
    }
    __syncthreads();

    if (t == 0) {
        float f3 = red[0][0], f4 = red[0][1], f5 = red[0][2];
        #pragma unroll
        for (int w = 1; w < 8; ++w) {
            f3 = fmaxf(f3, red[w][0]);
            f4 = fmaxf(f4, red[w][1]);
            f5 = fmaxf(f5, red[w][2]);
        }
        float lg[10];
        float mx = -1e30f;
        #pragma unroll
        for (int c = 0; c < 10; ++c) {
            lg[c] = fcb[c] + f3 * fcw[c*3+0] + f4 * fcw[c*3+1] + f5 * fcw[c*3+2];
            mx = fmaxf(mx, lg[c]);
        }
        float ssum = 0.f;
        #pragma unroll
        for (int c = 0; c < 10; ++c) ssum += expf(lg[c] - mx);
        const float lse = logf(ssum);
        #pragma unroll
        for (int c = 0; c < 10; ++c) out[b * 10 + c] = lg[c] - mx - lse;
    }
}

extern "C" void kernel_launch(void* const* d_in, const int* in_sizes, int n_in,
                              void* d_out, int out_size, void* d_ws, size_t ws_size,
                              hipStream_t stream) {
    const int*   sent = (const int*)  d_in[0];
    const float* emb  = (const float*)d_in[1];
    const float* k3   = (const float*)d_in[2];
    const float* b3   = (const float*)d_in[3];
    const float* k4   = (const float*)d_in[4];
    const float* b4   = (const float*)d_in[5];
    const float* k5   = (const float*)d_in[6];
    const float* b5   = (const float*)d_in[7];
    const float* fcw  = (const float*)d_in[8];
    const float* fcb  = (const float*)d_in[9];
    float* out = (float*)d_out;
    float* s   = (float*)d_ws;        // VROWS * 16 * 4 B = 3.2 MB

    const int nblk = (VROWS + 63) / 64;   // 782 blocks, 64 rows each
    vocab_scores_mfma<<<nblk, 256, 0, stream>>>(emb, k3, k4, k5, s);
    textcnn_finish<<<NSENT, 512, 0, stream>>>(sent, s, b3, b4, b5, fcw, fcb, out);
}